// Round 10
// baseline (451.654 us; speedup 1.0000x reference)
//
#include <hip/hip_runtime.h>

#define BB   8
#define DD   128
#define HHH  4
#define NNN  2048
#define MMM  2048
#define DH   32
#define TN   8      // score rows per attention block (4 waves x 2 rows)
#define SCPAD 34    // Sc lane stride in floats (8B-aligned float2, 2-way banks)
#define SCROWS (64 * SCPAD)

typedef float v2f __attribute__((ext_vector_type(2)));

// ---------------------------------------------------------------- GEMM
// MODE 0: qkv proj  -> out[b][h][n][e]  (c = e*4 + h head-split transpose)
// MODE 1: plain bias -> out[b][c][n]
// MODE 2: bias + BN + ReLU, input = concat(x, msg2) along channels
// MODE 3: bias       -> out[b][c][n]   (final delta)
template<int MODE>
__global__ __launch_bounds__(256)
void gemm_k(const float* __restrict__ W, const float* __restrict__ bias,
            const float* __restrict__ X0, const float* __restrict__ X1,
            float* __restrict__ out, int K, int Mrows,
            const float* __restrict__ g1, const float* __restrict__ be1,
            const float* __restrict__ mu1, const float* __restrict__ va1)
{
  __shared__ float Wt[32][132];
  __shared__ float Xl[32][64];
  const int tid = threadIdx.x;
  const int b   = blockIdx.x >> 5;
  const int n0  = (blockIdx.x & 31) << 6;
  const int rblk = blockIdx.y << 7;
  const int tx = tid & 15, ty = tid >> 4;

  float acc[8][4];
#pragma unroll
  for (int i = 0; i < 8; ++i)
#pragma unroll
    for (int j = 0; j < 4; ++j) acc[i][j] = 0.f;

  for (int k0 = 0; k0 < K; k0 += 32) {
#pragma unroll
    for (int i = 0; i < 4; ++i) {
      int idx = tid + i * 256;
      int r = idx >> 3, kv = (idx & 7) << 2;
      const float4 w4 = *(const float4*)&W[(size_t)(rblk + r) * K + k0 + kv];
      Wt[kv + 0][r] = w4.x; Wt[kv + 1][r] = w4.y;
      Wt[kv + 2][r] = w4.z; Wt[kv + 3][r] = w4.w;
    }
#pragma unroll
    for (int i = 0; i < 2; ++i) {
      int idx = tid + i * 256;
      int kk = idx >> 4, j4 = (idx & 15) << 2;
      int kg = k0 + kk;
      const float* src;
      if (MODE == 2)
        src = (kg < DD) ? &X0[((size_t)b * DD + kg) * NNN]
                        : &X1[((size_t)b * DD + (kg - DD)) * NNN];
      else
        src = &X0[((size_t)b * K + kg) * NNN];
      *(float4*)&Xl[kk][j4] = *(const float4*)&src[n0 + j4];
    }
    __syncthreads();
#pragma unroll
    for (int kk = 0; kk < 32; ++kk) {
      float a[8], bx[4];
      *(float4*)&a[0] = *(const float4*)&Wt[kk][ty * 8];
      *(float4*)&a[4] = *(const float4*)&Wt[kk][ty * 8 + 4];
      *(float4*)&bx[0] = *(const float4*)&Xl[kk][tx * 4];
#pragma unroll
      for (int i = 0; i < 8; ++i)
#pragma unroll
        for (int j = 0; j < 4; ++j) acc[i][j] = fmaf(a[i], bx[j], acc[i][j]);
    }
    __syncthreads();
  }

#pragma unroll
  for (int i = 0; i < 8; ++i) {
    const int r = rblk + ty * 8 + i;
    const float bv = bias[r];
    float scale = 1.f, shift = 0.f;
    if (MODE == 2) {
      const float inv = rsqrtf(va1[r] + 1e-5f);
      scale = g1[r] * inv;
      shift = be1[r] - mu1[r] * scale;
    }
#pragma unroll
    for (int j = 0; j < 4; ++j) {
      const int n = n0 + tx * 4 + j;
      float v = acc[i][j] + bv;
      if (MODE == 2) { v = fmaf(v, scale, shift); v = v > 0.f ? v : 0.f; }
      if (MODE == 0) {
        out[(((size_t)b * HHH + (r & 3)) * NNN + n) * DH + (r >> 2)] = v;
      } else {
        out[((size_t)b * Mrows + r) * NNN + n] = v;
      }
    }
  }
}

// ---------------------------------------------------------------- helpers
__device__ __forceinline__ void pk_fma(v2f& acc, v2f a, v2f b) {
  // D.x = a.x*b.x + acc.x ; D.y = a.y*b.y + acc.y  (2 fp32 FMA / instr)
  asm("v_pk_fma_f32 %0, %1, %2, %0" : "+v"(acc) : "v"(a), "v"(b));
}

__device__ __forceinline__ int dpp_scan_i32(int v) {
  v += __builtin_amdgcn_update_dpp(0, v, 0x111, 0xF, 0xF, true); // row_shr:1
  v += __builtin_amdgcn_update_dpp(0, v, 0x112, 0xF, 0xF, true); // row_shr:2
  v += __builtin_amdgcn_update_dpp(0, v, 0x114, 0xF, 0xF, true); // row_shr:4
  v += __builtin_amdgcn_update_dpp(0, v, 0x118, 0xF, 0xF, true); // row_shr:8
  v += __builtin_amdgcn_update_dpp(0, v, 0x142, 0xA, 0xF, true); // row_bcast:15
  v += __builtin_amdgcn_update_dpp(0, v, 0x143, 0xC, 0xF, true); // row_bcast:31
  return v;
}

__device__ __forceinline__ float dpp_sum_f32(float v) {
  // inclusive scan; lane 63 holds the 64-lane total
  float t;
#define DPPSTEP(ctrl, rm)                                                     \
  t = __uint_as_float((unsigned)__builtin_amdgcn_update_dpp(                  \
          0, (int)__float_as_uint(v), ctrl, rm, 0xF, true));                  \
  v += t;
  DPPSTEP(0x111, 0xF) DPPSTEP(0x112, 0xF) DPPSTEP(0x114, 0xF)
  DPPSTEP(0x118, 0xF) DPPSTEP(0x142, 0xA) DPPSTEP(0x143, 0xC)
#undef DPPSTEP
  return v;
}

__device__ __forceinline__ unsigned ordkey(float f) {
  unsigned b = __float_as_uint(f);
  return (b & 0x80000000u) ? ~b : (b | 0x80000000u);
}

__device__ __forceinline__ void transpose32(unsigned (&A)[32]) {
  unsigned m = 0x0000FFFFu;
#pragma unroll
  for (int j = 16; j != 0; j = j >> 1, m = m ^ (m << j)) {
#pragma unroll
    for (int k = 0; k < 32; ++k) {
      if (!(k & j)) {
        unsigned t = (A[k] ^ (A[k + j] >> j)) & m;
        A[k]     ^= t;
        A[k + j] ^= t << j;
      }
    }
  }
}

// ---------------------------------------------------------------- attention
// Round-3/9 structure (Sc stripe in LDS, Kl[64][36], two barriers per chunk,
// 2 blocks/CU) with the inner product issued as v_pk_fma_f32 (2 fp32 FMA per
// instruction -- the only way to the 157TF fp32 rate) and a DPP-based softmax
// denominator reduce (replaces a 5-deep ds_bpermute chain).
__global__ __launch_bounds__(256, 2)
void attn_k(const float* __restrict__ qt, const float* __restrict__ kt,
            const float* __restrict__ vt, float* __restrict__ msg)
{
  extern __shared__ char smem[];
  float* Sc = (float*)smem;                                  // [TN][64][SCPAD]
  float (*Kl)[36] = (float(*)[36])(smem + (size_t)TN * SCROWS * 4); // [64][36]

  const int tid  = threadIdx.x;
  const int wave = tid >> 6, lane = tid & 63;
  const int h = blockIdx.y, b = blockIdx.z;
  const int n0 = blockIdx.x * TN;
  const size_t bh = (size_t)b * HHH + h;
  const float* kbase = kt + bh * MMM * DH;
  const float* vbase = vt + bh * MMM * DH;
  const float* qbase = qt + (bh * NNN + n0) * DH;

  // q rows as even/odd v2f pairs (natural layout for pk_fma)
  v2f q0p[16], q1p[16];
  {
    const float4* qr0 = (const float4*)(qbase + (size_t)(wave * 2 + 0) * DH);
    const float4* qr1 = (const float4*)(qbase + (size_t)(wave * 2 + 1) * DH);
#pragma unroll
    for (int i = 0; i < 8; ++i) {
      const float4 t0 = qr0[i], t1 = qr1[i];
      q0p[2*i].x = t0.x; q0p[2*i].y = t0.y;
      q0p[2*i+1].x = t0.z; q0p[2*i+1].y = t0.w;
      q1p[2*i].x = t1.x; q1p[2*i].y = t1.y;
      q1p[2*i+1].x = t1.z; q1p[2*i+1].y = t1.w;
    }
  }

  float* s0 = Sc + (size_t)(wave * 2 + 0) * SCROWS + lane * SCPAD;
  float* s1 = Sc + (size_t)(wave * 2 + 1) * SCROWS + lane * SCPAD;

  // ---- phase 1: scores (unscaled), 2-deep prefetch, pk_fma inner loop ----
  const float4* kg4 = (const float4*)kbase;
  const int m0 = tid >> 3, e0 = (tid & 7) << 2;

  auto chunk = [&](int c, float4& f0, float4& f1) {
    __syncthreads();                     // prev chunk's reads done
    *(float4*)&Kl[m0][e0]      = f0;
    *(float4*)&Kl[m0 + 32][e0] = f1;
    if (c + 2 < 32) {                    // issue chunk c+2 (2-deep)
      f0 = kg4[(c + 2) * 512 + tid];
      f1 = kg4[(c + 2) * 512 + tid + 256];
    }
    __syncthreads();                     // writes visible
    v2f acc0; acc0.x = 0.f; acc0.y = 0.f;
    v2f acc1; acc1.x = 0.f; acc1.y = 0.f;
#pragma unroll
    for (int i = 0; i < 8; ++i) {
      const float4 kv4 = *(const float4*)&Kl[lane][i * 4];
      v2f k01; k01.x = kv4.x; k01.y = kv4.y;
      v2f k23; k23.x = kv4.z; k23.y = kv4.w;
      pk_fma(acc0, q0p[2*i],   k01);
      pk_fma(acc0, q0p[2*i+1], k23);
      pk_fma(acc1, q1p[2*i],   k01);
      pk_fma(acc1, q1p[2*i+1], k23);
    }
    s0[c] = acc0.x + acc0.y;             // 2-way bank (free)
    s1[c] = acc1.x + acc1.y;
  };

  float4 pA0 = kg4[tid],       pA1 = kg4[tid + 256];        // chunk 0
  float4 pB0 = kg4[512 + tid], pB1 = kg4[512 + tid + 256];  // chunk 1
  for (int c = 0; c < 32; c += 2) {
    chunk(c,     pA0, pA1);
    chunk(c + 1, pB0, pB1);
  }
  __syncthreads();                       // all waves done with Kl (scratch reuse)

  // ---- phase 2: bitplanes + packed 2-row radix top-32 ----
  unsigned A0[32], A1[32];
#pragma unroll
  for (int i = 0; i < 16; ++i) {
    const float2 v0 = *(const float2*)&s0[2 * i];
    const float2 v1 = *(const float2*)&s1[2 * i];
    A0[31 - 2 * i]     = ordkey(v0.x);
    A0[31 - 2 * i - 1] = ordkey(v0.y);
    A1[31 - 2 * i]     = ordkey(v1.x);
    A1[31 - 2 * i - 1] = ordkey(v1.y);
  }
  transpose32(A0);
  transpose32(A1);

  unsigned act0 = ~0u, act1 = ~0u, def0 = 0u, def1 = 0u, tau0 = 0u, tau1 = 0u;
  int Kq0 = 32, Kq1 = 32, rem0 = MMM, rem1 = MMM;
  bool done0 = false, done1 = false;

#pragma unroll
  for (int g = 0; g < 4; ++g) {          // 4 groups x 8 bits, uniform skip
    if (!(done0 && done1)) {
#pragma unroll
      for (int ii = 0; ii < 8; ++ii) {
        const int i = g * 8 + ii;        // compile-time index
        const unsigned h0 = act0 & A0[i];
        const unsigned h1 = act1 & A1[i];
        int pk = __builtin_popcount(h0) | (__builtin_popcount(h1) << 16);
        pk = dpp_scan_i32(pk);
        const int s = __builtin_amdgcn_readlane(pk, 63);
        const int c0 = s & 0xFFFF, c1 = (int)((unsigned)s >> 16);
        if (!done0) {
          if (c0 >= Kq0) { act0 = h0; tau0 |= 1u << (31 - i); rem0 = c0; }
          else { Kq0 -= c0; def0 |= h0; act0 &= ~A0[i]; rem0 -= c0; }
          done0 = (rem0 == Kq0);
        }
        if (!done1) {
          if (c1 >= Kq1) { act1 = h1; tau1 |= 1u << (31 - i); rem1 = c1; }
          else { Kq1 -= c1; def1 |= h1; act1 &= ~A1[i]; rem1 -= c1; }
          done1 = (rem1 == Kq1);
        }
      }
    }
  }

  // ---- per-row: tie fixup (rare), softmax (tau-shifted), P*V ----
  float* scrP = (float*)&Kl[0][0] + wave * 64;   // 32 p + 32 m per wave
  int*   scrM = (int*)(scrP + 32);
  const int e = lane & 31, half = lane >> 5;
  const float rs = 0.17677669529663687f;         // 1/sqrt(32)

#pragma unroll
  for (int r = 0; r < 2; ++r) {
    unsigned a_r = (r == 0) ? act0 : act1;
    const bool done_r = (r == 0) ? done0 : done1;
    const int  Kq_r   = (r == 0) ? Kq0 : Kq1;
    if (!done_r) {                       // ties: index-order fixup (uniform)
      unsigned sact = 0u;
      int remq = Kq_r;
      for (int j = 0; j < 32 && remq > 0; ++j) {
        const unsigned long long bal = __ballot((a_r >> j) & 1u);
        const int cnt = __popcll(bal);
        const int take = cnt < remq ? cnt : remq;
        const unsigned long long below = bal & ((1ull << lane) - 1ull);
        if (((a_r >> j) & 1u) && (int)__popcll(below) < take)
          sact |= 1u << j;
        remq -= take;
      }
      a_r = sact;
    }
    const unsigned sel = ((r == 0) ? def0 : def1) | a_r;
    const unsigned tau_r = (r == 0) ? tau0 : tau1;
    const unsigned tb = (tau_r & 0x80000000u) ? (tau_r & 0x7FFFFFFFu) : ~tau_r;
    const float tauf = __uint_as_float(tb);
    const float* srow = (r == 0) ? s0 : s1;

    const int ns = __builtin_popcount(sel);
    int pos = dpp_scan_i32(ns) - ns;     // exclusive offset
    asm volatile("s_waitcnt lgkmcnt(0)" ::: "memory");
    unsigned mrem = sel;
    while (mrem) {
      const int j = __ffs(mrem) - 1; mrem &= mrem - 1;
      scrP[pos] = __expf((srow[j] - tauf) * rs);
      scrM[pos] = j * 64 + lane;
      ++pos;
    }
    asm volatile("s_waitcnt lgkmcnt(0)" ::: "memory");

    const float pmine = (lane < 32) ? scrP[lane] : 0.f;
    const float tot = __uint_as_float(
        __builtin_amdgcn_readlane(__float_as_uint(dpp_sum_f32(pmine)), 63));
    const float rinv = 1.0f / tot;

    float accv = 0.f;
#pragma unroll
    for (int jj = 0; jj < 16; ++jj) {
      const int j2 = jj * 2 + half;
      const float pj = scrP[j2];
      const int   mj = scrM[j2];
      accv = fmaf(pj, vbase[(size_t)mj * DH + e], accv);
    }
    accv += __shfl_xor(accv, 32);
    accv *= rinv;
    if (lane < 32)
      msg[((size_t)b * DD + (e * HHH + h)) * NNN + (n0 + wave * 2 + r)] = accv;
  }
}

// ---------------------------------------------------------------- launch
extern "C" void kernel_launch(void* const* d_in, const int* in_sizes, int n_in,
                              void* d_out, int out_size, void* d_ws, size_t ws_size,
                              hipStream_t stream)
{
  const float* x   = (const float*)d_in[0];
  const float* src = (const float*)d_in[1];
  const float* Wq  = (const float*)d_in[2];
  const float* bq  = (const float*)d_in[3];
  const float* Wk  = (const float*)d_in[4];
  const float* bk  = (const float*)d_in[5];
  const float* Wv  = (const float*)d_in[6];
  const float* bv  = (const float*)d_in[7];
  const float* Wm  = (const float*)d_in[8];
  const float* bm  = (const float*)d_in[9];
  const float* W1  = (const float*)d_in[10];
  const float* b1  = (const float*)d_in[11];
  const float* g1  = (const float*)d_in[12];
  const float* be1 = (const float*)d_in[13];
  const float* mu1 = (const float*)d_in[14];
  const float* va1 = (const float*)d_in[15];
  const float* W2  = (const float*)d_in[16];
  const float* b2  = (const float*)d_in[17];

  float* ws = (float*)d_ws;
  const size_t SEG = 2097152;
  float* q_t  = ws;
  float* k_t  = ws + SEG;
  float* v_t  = ws + 2 * SEG;
  float* msg  = ws + 3 * SEG;
  float* msg2 = ws;
  float* z    = ws + SEG;

  const dim3 blk(256);
  const dim3 g128(256, 1), g256(256, 2);

  gemm_k<0><<<g128, blk, 0, stream>>>(Wq, bq, x,   nullptr, q_t, 128, 128,
                                      nullptr, nullptr, nullptr, nullptr);
  gemm_k<0><<<g128, blk, 0, stream>>>(Wk, bk, src, nullptr, k_t, 128, 128,
                                      nullptr, nullptr, nullptr, nullptr);
  gemm_k<0><<<g128, blk, 0, stream>>>(Wv, bv, src, nullptr, v_t, 128, 128,
                                      nullptr, nullptr, nullptr, nullptr);

  const size_t smem = (size_t)TN * SCROWS * 4 + 64 * 36 * 4;   // 78848 B
  hipFuncSetAttribute(reinterpret_cast<const void*>(attn_k),
                      hipFuncAttributeMaxDynamicSharedMemorySize, (int)smem);
  const dim3 ga(NNN / TN, HHH, BB);
  attn_k<<<ga, blk, smem, stream>>>(q_t, k_t, v_t, msg);

  gemm_k<1><<<g128, blk, 0, stream>>>(Wm, bm, msg, nullptr, msg2, 128, 128,
                                      nullptr, nullptr, nullptr, nullptr);
  gemm_k<2><<<g256, blk, 0, stream>>>(W1, b1, x, msg2, z, 256, 256,
                                      g1, be1, mu1, va1);
  gemm_k<3><<<g128, blk, 0, stream>>>(W2, b2, z, nullptr, (float*)d_out, 256, 128,
                                      nullptr, nullptr, nullptr, nullptr);
}